// Round 2
// baseline (160.952 us; speedup 1.0000x reference)
//
#include <hip/hip_runtime.h>
#include <hip/hip_bf16.h>
#include <cmath>

// GRU cell fused: B=8192, I=H=1024, fp32 in/out, bf16 MFMA compute.
// Round 2: double-buffered LDS (80KB) + deferred vmcnt drain (T3-minimum),
//          setprio around MFMA (T5), merged prepass (1 launch).
// ws layout (ushort elems):
//   wsIn  @ 0        : [64 mtile][32 kstep][128x32 swz]  = 8,388,608
//   wsHx  @ 8388608  : same                               = 8,388,608
//   wsWih @ 16777216 : [32 ntile][32 kstep][64x32 swz]    = 2,097,152
//   wsWhh @ 18874368 : same                               = 2,097,152
//   wsWc  @ 20971520 : [16 ntile][32 kstep][64x32 swz]    = 1,048,576
//   wsWhc @ 22020096 : same                               = 1,048,576

typedef __attribute__((ext_vector_type(8))) short bf16x8;
typedef __attribute__((ext_vector_type(4))) float f32x4;
typedef unsigned int u32;

typedef const __attribute__((address_space(1))) u32 gu32;
typedef __attribute__((address_space(3))) u32 su32;

__device__ __forceinline__ unsigned short f2bf(float f) {
  union { float f; u32 u; } v; v.f = f;
  u32 u = v.u;
  u += 0x7FFFu + ((u >> 16) & 1u);   // RTNE
  return (unsigned short)(u >> 16);
}

__device__ __forceinline__ void gload16(void* ldsp, const void* gp) {
  __builtin_amdgcn_global_load_lds((gu32*)gp, (su32*)ldsp, 16, 0, 0);
}

__device__ __forceinline__ float sigmf(float x) { return 1.0f / (1.0f + __expf(-x)); }

// ---------------- merged prepass: batch + weights fp32 -> bf16 swizzled tiles ----------------
__global__ __launch_bounds__(256) void cvt_all(
    const float* __restrict__ In, const float* __restrict__ Hx,
    const float* __restrict__ Wih, const float* __restrict__ Whh,
    const float* __restrict__ Wc,  const float* __restrict__ Whc,
    unsigned short* __restrict__ wsIn, unsigned short* __restrict__ wsHx,
    unsigned short* __restrict__ wsWih, unsigned short* __restrict__ wsWhh,
    unsigned short* __restrict__ wsWc,  unsigned short* __restrict__ wsWhc)
{
  int bid = blockIdx.x;
  if (bid < 8192) {
    // ---- batch path: 2 * 1M 16B-slots ----
    int gid = bid * 256 + threadIdx.x;
    const float* src; unsigned short* dst; int idx;
    if (gid < (1 << 20)) { src = In; dst = wsIn; idx = gid; }
    else                 { src = Hx; dst = wsHx; idx = gid - (1 << 20); }
    int m = idx >> 7;          // row 0..8191
    int t = idx & 127;         // 16B slot within row; k0 = t*8
    const float4* s = (const float4*)(src + (size_t)m * 1024 + t * 8);
    float4 a = s[0], b = s[1];
    int row = m & 127;
    size_t tile = (size_t)(m >> 7) * 32 + (t >> 2);
    int sw = (t & 3) ^ ((row >> 1) & 3);
    bf16x8 v;
    v[0] = (short)f2bf(a.x); v[1] = (short)f2bf(a.y); v[2] = (short)f2bf(a.z); v[3] = (short)f2bf(a.w);
    v[4] = (short)f2bf(b.x); v[5] = (short)f2bf(b.y); v[6] = (short)f2bf(b.z); v[7] = (short)f2bf(b.w);
    *(bf16x8*)(dst + tile * 4096 + row * 32 + sw * 8) = v;
  } else {
    // ---- weight path: fp32 [K][N] -> bf16 W^T swizzled tiles ----
    int wb = bid - 8192;           // 0..3071
    const float* W; unsigned short* dst; int NW; int local;
    if (wb < 1024)      { W = Wih; dst = wsWih; NW = 2048; local = wb; }
    else if (wb < 2048) { W = Whh; dst = wsWhh; NW = 2048; local = wb - 1024; }
    else if (wb < 2560) { W = Wc;  dst = wsWc;  NW = 1024; local = wb - 2048; }
    else                { W = Whc; dst = wsWhc; NW = 1024; local = wb - 2560; }
    int nb = local >> 5, kb = local & 31;
    int n  = nb * 64 + (threadIdx.x & 63);
    int k0 = kb * 32 + (threadIdx.x >> 6) * 8;
    unsigned short h[8];
    #pragma unroll
    for (int b = 0; b < 8; ++b) h[b] = f2bf(W[(size_t)(k0 + b) * NW + n]);
    int row = n & 63;
    size_t tile = (size_t)(n >> 6) * 32 + (k0 >> 5);
    int sw = ((k0 >> 3) & 3) ^ ((row >> 1) & 3);
    bf16x8 v;
    #pragma unroll
    for (int b = 0; b < 8; ++b) v[b] = (short)h[b];
    *(bf16x8*)(dst + tile * 2048 + row * 32 + sw * 8) = v;
  }
}

// ---------------- fused GEMM + GRU epilogue ----------------
// block: 256 thr = 4 waves (2x2), tile BM=128 x BN=64, BK=32, double-buffered.
// LDS buffer (ushort, per buf 20480): sIn[0,4096) sHx[4096,8192) W tiles t=0..5 at 8192+t*2048
//   t: 0=Wih_z 1=Wih_r 2=Whh_z 3=Whh_r 4=Wc 5=Whc
__global__ __launch_bounds__(256, 2) void gru_gemm(
    const unsigned short* __restrict__ wsIn, const unsigned short* __restrict__ wsHx,
    const unsigned short* __restrict__ wsWih, const unsigned short* __restrict__ wsWhh,
    const unsigned short* __restrict__ wsWc, const unsigned short* __restrict__ wsWhc,
    const float* __restrict__ Hx,
    const float* __restrict__ bih, const float* __restrict__ bhh,
    const float* __restrict__ bc, const float* __restrict__ bhc,
    float* __restrict__ out)
{
  __shared__ unsigned short lds[40960];   // 80 KB = 2 x 40KB buffers
  const int tid  = threadIdx.x;
  const int lane = tid & 63;
  const int wave = tid >> 6;
  const int wm = wave >> 1, wn = wave & 1;
  const int bid = blockIdx.x;
  const int j = bid & 15;     // n-block (64 cols)
  const int i = bid >> 4;     // m-block (128 rows)

  // per-wave staging plan: 10 chunks of 1KB each (64 lanes x 16B)
  const unsigned short* srcB[10];
  int strd[10];
  #pragma unroll
  for (int c0 = 0; c0 < 10; ++c0) {
    int c = wave * 10 + c0;
    const unsigned short* p; int st;
    if (c < 8)       { p = wsIn + (size_t)i * 131072 + c * 512;        st = 4096; }
    else if (c < 16) { p = wsHx + (size_t)i * 131072 + (c - 8) * 512;  st = 4096; }
    else {
      int t = (c - 16) >> 2, cc = (c - 16) & 3;
      const unsigned short* base; int nb;
      if (t == 0)      { base = wsWih; nb = j; }
      else if (t == 1) { base = wsWih; nb = j + 16; }
      else if (t == 2) { base = wsWhh; nb = j; }
      else if (t == 3) { base = wsWhh; nb = j + 16; }
      else if (t == 4) { base = wsWc;  nb = j; }
      else             { base = wsWhc; nb = j; }
      p = base + (size_t)nb * 65536 + cc * 512;
      st = 2048;
    }
    srcB[c0] = p + lane * 8;
    strd[c0] = st;
  }
  const int stageOff = (wave * 10) * 512;   // within a buffer

  f32x4 accZ[4][2], accR[4][2], accC[4][2], accH[4][2];
  #pragma unroll
  for (int a = 0; a < 4; ++a)
    #pragma unroll
    for (int b = 0; b < 2; ++b) {
      accZ[a][b] = (f32x4)(0.0f); accR[a][b] = (f32x4)(0.0f);
      accC[a][b] = (f32x4)(0.0f); accH[a][b] = (f32x4)(0.0f);
    }

  const int r15 = lane & 15;
  const int q   = lane >> 4;

  int aOff[4], wOff[2];
  #pragma unroll
  for (int mr = 0; mr < 4; ++mr) {
    int row = wm * 64 + mr * 16 + r15;
    aOff[mr] = row * 32 + ((q ^ ((row >> 1) & 3)) << 3);
  }
  #pragma unroll
  for (int nr = 0; nr < 2; ++nr) {
    int row = wn * 32 + nr * 16 + r15;
    wOff[nr] = row * 32 + ((q ^ ((row >> 1) & 3)) << 3);
  }

  auto stage = [&](int bufBase, int s) {
    #pragma unroll
    for (int c0 = 0; c0 < 10; ++c0)
      gload16((void*)&lds[bufBase + stageOff + c0 * 512],
              (const void*)(srcB[c0] + (size_t)s * strd[c0]));
  };

  auto compute = [&](const unsigned short* __restrict__ L) {
    bf16x8 aIn[4], aHx[4];
    #pragma unroll
    for (int mr = 0; mr < 4; ++mr) {
      aIn[mr] = *(const bf16x8*)&L[aOff[mr]];
      aHx[mr] = *(const bf16x8*)&L[4096 + aOff[mr]];
    }
    bf16x8 wf[6][2];
    #pragma unroll
    for (int t = 0; t < 6; ++t)
      #pragma unroll
      for (int nr = 0; nr < 2; ++nr)
        wf[t][nr] = *(const bf16x8*)&L[8192 + t * 2048 + wOff[nr]];

    __builtin_amdgcn_s_setprio(1);
    #pragma unroll
    for (int mr = 0; mr < 4; ++mr)
      #pragma unroll
      for (int nr = 0; nr < 2; ++nr) {
        accZ[mr][nr] = __builtin_amdgcn_mfma_f32_16x16x32_bf16(aIn[mr], wf[0][nr], accZ[mr][nr], 0, 0, 0);
        accZ[mr][nr] = __builtin_amdgcn_mfma_f32_16x16x32_bf16(aHx[mr], wf[2][nr], accZ[mr][nr], 0, 0, 0);
        accR[mr][nr] = __builtin_amdgcn_mfma_f32_16x16x32_bf16(aIn[mr], wf[1][nr], accR[mr][nr], 0, 0, 0);
        accR[mr][nr] = __builtin_amdgcn_mfma_f32_16x16x32_bf16(aHx[mr], wf[3][nr], accR[mr][nr], 0, 0, 0);
        accC[mr][nr] = __builtin_amdgcn_mfma_f32_16x16x32_bf16(aIn[mr], wf[4][nr], accC[mr][nr], 0, 0, 0);
        accH[mr][nr] = __builtin_amdgcn_mfma_f32_16x16x32_bf16(aHx[mr], wf[5][nr], accH[mr][nr], 0, 0, 0);
      }
    __builtin_amdgcn_s_setprio(0);
  };

  // prologue: stage step 0 into buf0, drain
  stage(0, 0);
  __syncthreads();

  // main loop: 2 steps per iteration, static buffer addresses
  #pragma unroll 1
  for (int it = 0; it < 16; ++it) {
    const int s = it * 2;
    // --- step s (buf0) ---
    stage(20480, s + 1);                         // next tile -> buf1
    __builtin_amdgcn_sched_barrier(0);
    compute(&lds[0]);
    __syncthreads();                             // drains vmcnt for buf1 stage
    // --- step s+1 (buf1) ---
    if (it < 15) stage(0, s + 2);                // next tile -> buf0
    __builtin_amdgcn_sched_barrier(0);
    compute(&lds[20480]);
    __syncthreads();                             // drains vmcnt for buf0 stage
  }

  // epilogue: D layout col = lane&15 (n), row = q*4+v (m)
  const int n0 = j * 64 + wn * 32;
  const int m0 = i * 128 + wm * 64;
  #pragma unroll
  for (int nr = 0; nr < 2; ++nr) {
    int n = n0 + nr * 16 + r15;
    float bz  = bih[n] + bhh[n];
    float br  = bih[1024 + n] + bhh[1024 + n];
    float bcv = bc[n], bhcv = bhc[n];
    #pragma unroll
    for (int mr = 0; mr < 4; ++mr) {
      #pragma unroll
      for (int v = 0; v < 4; ++v) {
        int m = m0 + mr * 16 + q * 4 + v;
        float z  = sigmf(accZ[mr][nr][v] + bz);
        float rr = sigmf(accR[mr][nr][v] + br);
        float cd = tanhf(accC[mr][nr][v] + bcv + rr * (accH[mr][nr][v] + bhcv));
        float h  = Hx[(size_t)m * 1024 + n];
        out[(size_t)m * 1024 + n] = (1.0f - z) * h + z * cd;
      }
    }
  }
}

// ---------------- fallback (ws too small): fp32 LDS-tiled, slow but correct ----------------
__global__ __launch_bounds__(256) void gru_fallback(
    const float* __restrict__ In, const float* __restrict__ Hx,
    const float* __restrict__ Wih, const float* __restrict__ bih,
    const float* __restrict__ Whh, const float* __restrict__ bhh,
    const float* __restrict__ Wc, const float* __restrict__ bc,
    const float* __restrict__ Whc, const float* __restrict__ bhc,
    float* __restrict__ out)
{
  __shared__ float sIn[64][17], sHx[64][17];
  __shared__ float sW[6][16][68];
  const int tid = threadIdx.x;
  const int j = blockIdx.x & 15, i = blockIdx.x >> 4;
  const int tx = tid & 15, ty = tid >> 4;
  float accZ[4][4] = {}, accR[4][4] = {}, accC[4][4] = {}, accH[4][4] = {};
  const int ms = tid >> 2, kq = (tid & 3) * 4;
  const int wk = tid >> 4, wn4 = (tid & 15) * 4;
  for (int k0 = 0; k0 < 1024; k0 += 16) {
    __syncthreads();
    {
      float4 a = *(const float4*)&In[(size_t)(i * 64 + ms) * 1024 + k0 + kq];
      sIn[ms][kq] = a.x; sIn[ms][kq + 1] = a.y; sIn[ms][kq + 2] = a.z; sIn[ms][kq + 3] = a.w;
      float4 b = *(const float4*)&Hx[(size_t)(i * 64 + ms) * 1024 + k0 + kq];
      sHx[ms][kq] = b.x; sHx[ms][kq + 1] = b.y; sHx[ms][kq + 2] = b.z; sHx[ms][kq + 3] = b.w;
    }
    {
      float4 w0 = *(const float4*)&Wih[(size_t)(k0 + wk) * 2048 + j * 64 + wn4];
      float4 w1 = *(const float4*)&Wih[(size_t)(k0 + wk) * 2048 + 1024 + j * 64 + wn4];
      float4 w2 = *(const float4*)&Whh[(size_t)(k0 + wk) * 2048 + j * 64 + wn4];
      float4 w3 = *(const float4*)&Whh[(size_t)(k0 + wk) * 2048 + 1024 + j * 64 + wn4];
      float4 w4 = *(const float4*)&Wc[(size_t)(k0 + wk) * 1024 + j * 64 + wn4];
      float4 w5 = *(const float4*)&Whc[(size_t)(k0 + wk) * 1024 + j * 64 + wn4];
      sW[0][wk][wn4] = w0.x; sW[0][wk][wn4+1] = w0.y; sW[0][wk][wn4+2] = w0.z; sW[0][wk][wn4+3] = w0.w;
      sW[1][wk][wn4] = w1.x; sW[1][wk][wn4+1] = w1.y; sW[1][wk][wn4+2] = w1.z; sW[1][wk][wn4+3] = w1.w;
      sW[2][wk][wn4] = w2.x; sW[2][wk][wn4+1] = w2.y; sW[2][wk][wn4+2] = w2.z; sW[2][wk][wn4+3] = w2.w;
      sW[3][wk][wn4] = w3.x; sW[3][wk][wn4+1] = w3.y; sW[3][wk][wn4+2] = w3.z; sW[3][wk][wn4+3] = w3.w;
      sW[4][wk][wn4] = w4.x; sW[4][wk][wn4+1] = w4.y; sW[4][wk][wn4+2] = w4.z; sW[4][wk][wn4+3] = w4.w;
      sW[5][wk][wn4] = w5.x; sW[5][wk][wn4+1] = w5.y; sW[5][wk][wn4+2] = w5.z; sW[5][wk][wn4+3] = w5.w;
    }
    __syncthreads();
    for (int kk = 0; kk < 16; ++kk) {
      float aI[4], aH[4];
      #pragma unroll
      for (int im = 0; im < 4; ++im) { aI[im] = sIn[ty * 4 + im][kk]; aH[im] = sHx[ty * 4 + im][kk]; }
      #pragma unroll
      for (int jn = 0; jn < 4; ++jn) {
        float w0 = sW[0][kk][tx * 4 + jn], w1 = sW[1][kk][tx * 4 + jn], w2 = sW[2][kk][tx * 4 + jn];
        float w3 = sW[3][kk][tx * 4 + jn], w4 = sW[4][kk][tx * 4 + jn], w5 = sW[5][kk][tx * 4 + jn];
        #pragma unroll
        for (int im = 0; im < 4; ++im) {
          accZ[im][jn] += aI[im] * w0 + aH[im] * w2;
          accR[im][jn] += aI[im] * w1 + aH[im] * w3;
          accC[im][jn] += aI[im] * w4;
          accH[im][jn] += aH[im] * w5;
        }
      }
    }
  }
  #pragma unroll
  for (int jn = 0; jn < 4; ++jn) {
    int n = j * 64 + tx * 4 + jn;
    float bz  = bih[n] + bhh[n];
    float br  = bih[1024 + n] + bhh[1024 + n];
    float bcv = bc[n], bhcv = bhc[n];
    #pragma unroll
    for (int im = 0; im < 4; ++im) {
      int m = i * 64 + ty * 4 + im;
      float z  = sigmf(accZ[im][jn] + bz);
      float rr = sigmf(accR[im][jn] + br);
      float cd = tanhf(accC[im][jn] + bcv + rr * (accH[im][jn] + bhcv));
      float h  = Hx[(size_t)m * 1024 + n];
      out[(size_t)m * 1024 + n] = (1.0f - z) * h + z * cd;
    }
  }
}

extern "C" void kernel_launch(void* const* d_in, const int* in_sizes, int n_in,
                              void* d_out, int out_size, void* d_ws, size_t ws_size,
                              hipStream_t stream) {
  const float* In  = (const float*)d_in[0];
  const float* Hx  = (const float*)d_in[1];
  const float* Wih = (const float*)d_in[2];
  const float* bih = (const float*)d_in[3];
  const float* Whh = (const float*)d_in[4];
  const float* bhh = (const float*)d_in[5];
  const float* Wc  = (const float*)d_in[6];
  const float* bc  = (const float*)d_in[7];
  const float* Whc = (const float*)d_in[8];
  const float* bhc = (const float*)d_in[9];
  float* out = (float*)d_out;

  const size_t WS_NEED = 46137344ull;
  if (ws_size >= WS_NEED) {
    unsigned short* ws    = (unsigned short*)d_ws;
    unsigned short* wsIn  = ws;
    unsigned short* wsHx  = ws + 8388608;
    unsigned short* wsWih = ws + 16777216;
    unsigned short* wsWhh = ws + 18874368;
    unsigned short* wsWc  = ws + 20971520;
    unsigned short* wsWhc = ws + 22020096;
    cvt_all<<<11264, 256, 0, stream>>>(In, Hx, Wih, Whh, Wc, Whc,
                                       wsIn, wsHx, wsWih, wsWhh, wsWc, wsWhc);
    gru_gemm<<<1024, 256, 0, stream>>>(wsIn, wsHx, wsWih, wsWhh, wsWc, wsWhc,
                                       Hx, bih, bhh, bc, bhc, out);
  } else {
    gru_fallback<<<2048, 256, 0, stream>>>(In, Hx, Wih, bih, Whh, bhh, Wc, bc, Whc, bhc, out);
  }
}

// Round 3
// 135.627 us; speedup vs baseline: 1.1867x; 1.1867x over previous
//
#include <hip/hip_runtime.h>
#include <hip/hip_bf16.h>
#include <cmath>

// GRU cell fused: B=8192, I=H=1024, fp32 in/out, bf16 MFMA compute.
// Round 3: BM=256 x BN=64, 8 waves, 2-buffer pipeline with counted vmcnt(7)
//          (never 0 in loop), reads/MFMA interleaved per step, XCD swizzle.
// ws layout (ushort elems):
//   wsIn  @ 0        : [64 mtile][32 kstep][128x32 swz]  = 8,388,608
//   wsHx  @ 8388608  : same                               = 8,388,608
//   wsWih @ 16777216 : [32 ntile][32 kstep][64x32 swz]    = 2,097,152
//   wsWhh @ 18874368 : same                               = 2,097,152
//   wsWc  @ 20971520 : [16 ntile][32 kstep][64x32 swz]    = 1,048,576
//   wsWhc @ 22020096 : same                               = 1,048,576

typedef __attribute__((ext_vector_type(8))) short bf16x8;
typedef __attribute__((ext_vector_type(4))) float f32x4;
typedef unsigned int u32;

typedef const __attribute__((address_space(1))) u32 gu32;
typedef __attribute__((address_space(3))) u32 su32;

__device__ __forceinline__ unsigned short f2bf(float f) {
  union { float f; u32 u; } v; v.f = f;
  u32 u = v.u;
  u += 0x7FFFu + ((u >> 16) & 1u);   // RTNE
  return (unsigned short)(u >> 16);
}

__device__ __forceinline__ void gload16(void* ldsp, const void* gp) {
  __builtin_amdgcn_global_load_lds((gu32*)gp, (su32*)ldsp, 16, 0, 0);
}

__device__ __forceinline__ float sigmf(float x) { return 1.0f / (1.0f + __expf(-x)); }

// ---------------- merged prepass: batch + weights fp32 -> bf16 swizzled tiles ----------------
__global__ __launch_bounds__(256) void cvt_all(
    const float* __restrict__ In, const float* __restrict__ Hx,
    const float* __restrict__ Wih, const float* __restrict__ Whh,
    const float* __restrict__ Wc,  const float* __restrict__ Whc,
    unsigned short* __restrict__ wsIn, unsigned short* __restrict__ wsHx,
    unsigned short* __restrict__ wsWih, unsigned short* __restrict__ wsWhh,
    unsigned short* __restrict__ wsWc,  unsigned short* __restrict__ wsWhc)
{
  int bid = blockIdx.x;
  if (bid < 8192) {
    // ---- batch path: 2 * 1M 16B-slots ----
    int gid = bid * 256 + threadIdx.x;
    const float* src; unsigned short* dst; int idx;
    if (gid < (1 << 20)) { src = In; dst = wsIn; idx = gid; }
    else                 { src = Hx; dst = wsHx; idx = gid - (1 << 20); }
    int m = idx >> 7;          // row 0..8191
    int t = idx & 127;         // 16B slot within row; k0 = t*8
    const float4* s = (const float4*)(src + (size_t)m * 1024 + t * 8);
    float4 a = s[0], b = s[1];
    int row = m & 127;
    size_t tile = (size_t)(m >> 7) * 32 + (t >> 2);
    int sw = (t & 3) ^ ((row >> 1) & 3);
    bf16x8 v;
    v[0] = (short)f2bf(a.x); v[1] = (short)f2bf(a.y); v[2] = (short)f2bf(a.z); v[3] = (short)f2bf(a.w);
    v[4] = (short)f2bf(b.x); v[5] = (short)f2bf(b.y); v[6] = (short)f2bf(b.z); v[7] = (short)f2bf(b.w);
    *(bf16x8*)(dst + tile * 4096 + row * 32 + sw * 8) = v;
  } else {
    // ---- weight path: fp32 [K][N] -> bf16 W^T swizzled tiles ----
    int wb = bid - 8192;           // 0..3071
    const float* W; unsigned short* dst; int NW; int local;
    if (wb < 1024)      { W = Wih; dst = wsWih; NW = 2048; local = wb; }
    else if (wb < 2048) { W = Whh; dst = wsWhh; NW = 2048; local = wb - 1024; }
    else if (wb < 2560) { W = Wc;  dst = wsWc;  NW = 1024; local = wb - 2048; }
    else                { W = Whc; dst = wsWhc; NW = 1024; local = wb - 2560; }
    int nb = local >> 5, kb = local & 31;
    int n  = nb * 64 + (threadIdx.x & 63);
    int k0 = kb * 32 + (threadIdx.x >> 6) * 8;
    unsigned short h[8];
    #pragma unroll
    for (int b = 0; b < 8; ++b) h[b] = f2bf(W[(size_t)(k0 + b) * NW + n]);
    int row = n & 63;
    size_t tile = (size_t)(n >> 6) * 32 + (k0 >> 5);
    int sw = ((k0 >> 3) & 3) ^ ((row >> 1) & 3);
    bf16x8 v;
    #pragma unroll
    for (int b = 0; b < 8; ++b) v[b] = (short)h[b];
    *(bf16x8*)(dst + tile * 2048 + row * 32 + sw * 8) = v;
  }
}

// ---------------- fused GEMM + GRU epilogue ----------------
// block: 512 thr = 8 waves (4m x 2n), tile BM=256 x BN=64, BK=32.
// LDS: 2 buffers x 28672 ushorts. Per buffer:
//   In  [0,8192)      : 2 half-tiles of [128 rows][32 k] swz
//   Hx  [8192,16384)  : same
//   W   [16384,28672) : 6 tiles x [64 rows][32 k] swz; t: 0=Wih_z 1=Wih_r 2=Whh_z 3=Whh_r 4=Wc 5=Whc
// Pipeline: per step: {ds_reads + 48 MFMA (compiler-interleaved); lgkmcnt(0);
//   barrier; stage(this buf <- s+2); vmcnt(7); barrier}. vmcnt never drains to 0.
__global__ __launch_bounds__(512, 2) void gru_gemm(
    const unsigned short* __restrict__ wsIn, const unsigned short* __restrict__ wsHx,
    const unsigned short* __restrict__ wsWih, const unsigned short* __restrict__ wsWhh,
    const unsigned short* __restrict__ wsWc, const unsigned short* __restrict__ wsWhc,
    const float* __restrict__ Hx,
    const float* __restrict__ bih, const float* __restrict__ bhh,
    const float* __restrict__ bc, const float* __restrict__ bhc,
    float* __restrict__ out)
{
  __shared__ unsigned short lds[57344];      // 112 KB = 2 x 28672
  const int tid  = threadIdx.x;
  const int lane = tid & 63;
  const int wave = tid >> 6;                 // 0..7
  const int wm = wave >> 1, wn = wave & 1;   // 4m x 2n
  const int bid = blockIdx.x;
  const int swz = (bid & 7) * 64 + (bid >> 3);   // bijective XCD swizzle (512%8==0)
  const int j = swz & 15;                    // n-block (64 cols)
  const int i = swz >> 4;                    // m-block (256 rows), 0..31

  // stage plan: 56 chunks x 1KB (64 lanes x 16B); this wave's 7 chunks
  const unsigned short* srcB[7];
  int strd[7];
  #pragma unroll
  for (int c0 = 0; c0 < 7; ++c0) {
    int c = wave * 7 + c0;
    const unsigned short* p; int st;
    if (c < 16) {                              // In: chunks 0-15
      int mt = 2 * i + (c >> 3);
      p = wsIn + (size_t)mt * 131072 + (c & 7) * 512; st = 4096;
    } else if (c < 32) {                       // Hx: chunks 16-31
      int cc = c - 16; int mt = 2 * i + (cc >> 3);
      p = wsHx + (size_t)mt * 131072 + (cc & 7) * 512; st = 4096;
    } else {                                   // W: chunks 32-55
      int t = (c - 32) >> 2, cc = (c - 32) & 3;
      const unsigned short* base; int nb;
      if (t == 0)      { base = wsWih; nb = j; }
      else if (t == 1) { base = wsWih; nb = j + 16; }
      else if (t == 2) { base = wsWhh; nb = j; }
      else if (t == 3) { base = wsWhh; nb = j + 16; }
      else if (t == 4) { base = wsWc;  nb = j; }
      else             { base = wsWhc; nb = j; }
      p = base + (size_t)nb * 65536 + cc * 512; st = 2048;
    }
    srcB[c0] = p + lane * 8;
    strd[c0] = st;
  }
  const int ldsC = wave * 3584;               // this wave's chunk base within a buffer

  f32x4 accZ[4][2], accR[4][2], accC[4][2], accH[4][2];
  #pragma unroll
  for (int a = 0; a < 4; ++a)
    #pragma unroll
    for (int b = 0; b < 2; ++b) {
      accZ[a][b] = (f32x4)(0.0f); accR[a][b] = (f32x4)(0.0f);
      accC[a][b] = (f32x4)(0.0f); accH[a][b] = (f32x4)(0.0f);
    }

  const int r15 = lane & 15;
  const int q   = lane >> 4;

  int aOff[4], wOff[2];
  #pragma unroll
  for (int mr = 0; mr < 4; ++mr) {
    int gr = wm * 64 + mr * 16 + r15;                       // 0..255
    aOff[mr] = (gr >> 7) * 4096 + (gr & 127) * 32 + ((q ^ ((gr >> 1) & 3)) << 3);
  }
  #pragma unroll
  for (int nr = 0; nr < 2; ++nr) {
    int wr = wn * 32 + nr * 16 + r15;                       // 0..63
    wOff[nr] = 16384 + wr * 32 + ((q ^ ((wr >> 1) & 3)) << 3);
  }

  auto stage = [&](int B, int s) {
    #pragma unroll
    for (int c0 = 0; c0 < 7; ++c0)
      gload16((void*)&lds[B + ldsC + c0 * 512],
              (const void*)(srcB[c0] + (size_t)s * strd[c0]));
  };

  auto step = [&](int B, int s2) {
    bf16x8 aIn[4], aHx[4];
    #pragma unroll
    for (int mr = 0; mr < 4; ++mr) {
      aIn[mr] = *(const bf16x8*)&lds[B + aOff[mr]];
      aHx[mr] = *(const bf16x8*)&lds[B + 8192 + aOff[mr]];
    }
    __builtin_amdgcn_s_setprio(1);
    {  // z-gate: Wih_z (t0) with In, Whh_z (t2) with Hx
      bf16x8 wa[2], wb[2];
      #pragma unroll
      for (int nr = 0; nr < 2; ++nr) {
        wa[nr] = *(const bf16x8*)&lds[B + wOff[nr]];
        wb[nr] = *(const bf16x8*)&lds[B + 4096 + wOff[nr]];
      }
      #pragma unroll
      for (int mr = 0; mr < 4; ++mr)
        #pragma unroll
        for (int nr = 0; nr < 2; ++nr) {
          accZ[mr][nr] = __builtin_amdgcn_mfma_f32_16x16x32_bf16(aIn[mr], wa[nr], accZ[mr][nr], 0, 0, 0);
          accZ[mr][nr] = __builtin_amdgcn_mfma_f32_16x16x32_bf16(aHx[mr], wb[nr], accZ[mr][nr], 0, 0, 0);
        }
    }
    {  // r-gate: Wih_r (t1), Whh_r (t3)
      bf16x8 wa[2], wb[2];
      #pragma unroll
      for (int nr = 0; nr < 2; ++nr) {
        wa[nr] = *(const bf16x8*)&lds[B + 2048 + wOff[nr]];
        wb[nr] = *(const bf16x8*)&lds[B + 6144 + wOff[nr]];
      }
      #pragma unroll
      for (int mr = 0; mr < 4; ++mr)
        #pragma unroll
        for (int nr = 0; nr < 2; ++nr) {
          accR[mr][nr] = __builtin_amdgcn_mfma_f32_16x16x32_bf16(aIn[mr], wa[nr], accR[mr][nr], 0, 0, 0);
          accR[mr][nr] = __builtin_amdgcn_mfma_f32_16x16x32_bf16(aHx[mr], wb[nr], accR[mr][nr], 0, 0, 0);
        }
    }
    {  // c: Wc (t4) with In; h: Whc (t5) with Hx
      bf16x8 wa[2], wb[2];
      #pragma unroll
      for (int nr = 0; nr < 2; ++nr) {
        wa[nr] = *(const bf16x8*)&lds[B + 8192 + wOff[nr]];
        wb[nr] = *(const bf16x8*)&lds[B + 10240 + wOff[nr]];
      }
      #pragma unroll
      for (int mr = 0; mr < 4; ++mr)
        #pragma unroll
        for (int nr = 0; nr < 2; ++nr) {
          accC[mr][nr] = __builtin_amdgcn_mfma_f32_16x16x32_bf16(aIn[mr], wa[nr], accC[mr][nr], 0, 0, 0);
          accH[mr][nr] = __builtin_amdgcn_mfma_f32_16x16x32_bf16(aHx[mr], wb[nr], accH[mr][nr], 0, 0, 0);
        }
    }
    __builtin_amdgcn_s_setprio(0);
    // all this wave's ds_reads of buffer B complete before anyone overwrites it
    asm volatile("s_waitcnt lgkmcnt(0)" ::: "memory");
    __builtin_amdgcn_s_barrier();
    stage(B, s2);                                   // overwrite B with step s2
    // previously-staged buffer (7 older loads) must have landed; 7 newest stay in flight
    asm volatile("s_waitcnt vmcnt(7)" ::: "memory");
    __builtin_amdgcn_s_barrier();
  };

  // prologue: stage steps 0,1; wait for step-0's 7 loads only
  stage(0, 0);
  stage(28672, 1);
  asm volatile("s_waitcnt vmcnt(7)" ::: "memory");
  __builtin_amdgcn_s_barrier();

  #pragma unroll 1
  for (int it = 0; it < 16; ++it) {
    const int s = it * 2;
    step(0,     s + 2 <= 31 ? s + 2 : 31);   // clamp: tail re-stages step 31 (never read)
    step(28672, s + 3 <= 31 ? s + 3 : 31);
  }

  // epilogue: D layout col = lane&15 (n), row = q*4+v (m)
  const int n0 = j * 64 + wn * 32;
  const int m0 = i * 256 + wm * 64;
  #pragma unroll
  for (int nr = 0; nr < 2; ++nr) {
    int n = n0 + nr * 16 + r15;
    float bz  = bih[n] + bhh[n];
    float br  = bih[1024 + n] + bhh[1024 + n];
    float bcv = bc[n], bhcv = bhc[n];
    #pragma unroll
    for (int mr = 0; mr < 4; ++mr) {
      #pragma unroll
      for (int v = 0; v < 4; ++v) {
        int m = m0 + mr * 16 + q * 4 + v;
        float z  = sigmf(accZ[mr][nr][v] + bz);
        float rr = sigmf(accR[mr][nr][v] + br);
        float cd = tanhf(accC[mr][nr][v] + bcv + rr * (accH[mr][nr][v] + bhcv));
        float h  = Hx[(size_t)m * 1024 + n];
        out[(size_t)m * 1024 + n] = (1.0f - z) * h + z * cd;
      }
    }
  }
}

// ---------------- fallback (ws too small): fp32 LDS-tiled, slow but correct ----------------
__global__ __launch_bounds__(256) void gru_fallback(
    const float* __restrict__ In, const float* __restrict__ Hx,
    const float* __restrict__ Wih, const float* __restrict__ bih,
    const float* __restrict__ Whh, const float* __restrict__ bhh,
    const float* __restrict__ Wc, const float* __restrict__ bc,
    const float* __restrict__ Whc, const float* __restrict__ bhc,
    float* __restrict__ out)
{
  __shared__ float sIn[64][17], sHx[64][17];
  __shared__ float sW[6][16][68];
  const int tid = threadIdx.x;
  const int j = blockIdx.x & 15, i = blockIdx.x >> 4;
  const int tx = tid & 15, ty = tid >> 4;
  float accZ[4][4] = {}, accR[4][4] = {}, accC[4][4] = {}, accH[4][4] = {};
  const int ms = tid >> 2, kq = (tid & 3) * 4;
  const int wk = tid >> 4, wn4 = (tid & 15) * 4;
  for (int k0 = 0; k0 < 1024; k0 += 16) {
    __syncthreads();
    {
      float4 a = *(const float4*)&In[(size_t)(i * 64 + ms) * 1024 + k0 + kq];
      sIn[ms][kq] = a.x; sIn[ms][kq + 1] = a.y; sIn[ms][kq + 2] = a.z; sIn[ms][kq + 3] = a.w;
      float4 b = *(const float4*)&Hx[(size_t)(i * 64 + ms) * 1024 + k0 + kq];
      sHx[ms][kq] = b.x; sHx[ms][kq + 1] = b.y; sHx[ms][kq + 2] = b.z; sHx[ms][kq + 3] = b.w;
    }
    {
      float4 w0 = *(const float4*)&Wih[(size_t)(k0 + wk) * 2048 + j * 64 + wn4];
      float4 w1 = *(const float4*)&Wih[(size_t)(k0 + wk) * 2048 + 1024 + j * 64 + wn4];
      float4 w2 = *(const float4*)&Whh[(size_t)(k0 + wk) * 2048 + j * 64 + wn4];
      float4 w3 = *(const float4*)&Whh[(size_t)(k0 + wk) * 2048 + 1024 + j * 64 + wn4];
      float4 w4 = *(const float4*)&Wc[(size_t)(k0 + wk) * 1024 + j * 64 + wn4];
      float4 w5 = *(const float4*)&Whc[(size_t)(k0 + wk) * 1024 + j * 64 + wn4];
      sW[0][wk][wn4] = w0.x; sW[0][wk][wn4+1] = w0.y; sW[0][wk][wn4+2] = w0.z; sW[0][wk][wn4+3] = w0.w;
      sW[1][wk][wn4] = w1.x; sW[1][wk][wn4+1] = w1.y; sW[1][wk][wn4+2] = w1.z; sW[1][wk][wn4+3] = w1.w;
      sW[2][wk][wn4] = w2.x; sW[2][wk][wn4+1] = w2.y; sW[2][wk][wn4+2] = w2.z; sW[2][wk][wn4+3] = w2.w;
      sW[3][wk][wn4] = w3.x; sW[3][wk][wn4+1] = w3.y; sW[3][wk][wn4+2] = w3.z; sW[3][wk][wn4+3] = w3.w;
      sW[4][wk][wn4] = w4.x; sW[4][wk][wn4+1] = w4.y; sW[4][wk][wn4+2] = w4.z; sW[4][wk][wn4+3] = w4.w;
      sW[5][wk][wn4] = w5.x; sW[5][wk][wn4+1] = w5.y; sW[5][wk][wn4+2] = w5.z; sW[5][wk][wn4+3] = w5.w;
    }
    __syncthreads();
    for (int kk = 0; kk < 16; ++kk) {
      float aI[4], aH[4];
      #pragma unroll
      for (int im = 0; im < 4; ++im) { aI[im] = sIn[ty * 4 + im][kk]; aH[im] = sHx[ty * 4 + im][kk]; }
      #pragma unroll
      for (int jn = 0; jn < 4; ++jn) {
        float w0 = sW[0][kk][tx * 4 + jn], w1 = sW[1][kk][tx * 4 + jn], w2 = sW[2][kk][tx * 4 + jn];
        float w3 = sW[3][kk][tx * 4 + jn], w4 = sW[4][kk][tx * 4 + jn], w5 = sW[5][kk][tx * 4 + jn];
        #pragma unroll
        for (int im = 0; im < 4; ++im) {
          accZ[im][jn] += aI[im] * w0 + aH[im] * w2;
          accR[im][jn] += aI[im] * w1 + aH[im] * w3;
          accC[im][jn] += aI[im] * w4;
          accH[im][jn] += aH[im] * w5;
        }
      }
    }
  }
  #pragma unroll
  for (int jn = 0; jn < 4; ++jn) {
    int n = j * 64 + tx * 4 + jn;
    float bz  = bih[n] + bhh[n];
    float br  = bih[1024 + n] + bhh[1024 + n];
    float bcv = bc[n], bhcv = bhc[n];
    #pragma unroll
    for (int im = 0; im < 4; ++im) {
      int m = i * 64 + ty * 4 + im;
      float z  = sigmf(accZ[im][jn] + bz);
      float rr = sigmf(accR[im][jn] + br);
      float cd = tanhf(accC[im][jn] + bcv + rr * (accH[im][jn] + bhcv));
      float h  = Hx[(size_t)m * 1024 + n];
      out[(size_t)m * 1024 + n] = (1.0f - z) * h + z * cd;
    }
  }
}

extern "C" void kernel_launch(void* const* d_in, const int* in_sizes, int n_in,
                              void* d_out, int out_size, void* d_ws, size_t ws_size,
                              hipStream_t stream) {
  const float* In  = (const float*)d_in[0];
  const float* Hx  = (const float*)d_in[1];
  const float* Wih = (const float*)d_in[2];
  const float* bih = (const float*)d_in[3];
  const float* Whh = (const float*)d_in[4];
  const float* bhh = (const float*)d_in[5];
  const float* Wc  = (const float*)d_in[6];
  const float* bc  = (const float*)d_in[7];
  const float* Whc = (const float*)d_in[8];
  const float* bhc = (const float*)d_in[9];
  float* out = (float*)d_out;

  const size_t WS_NEED = 46137344ull;
  if (ws_size >= WS_NEED) {
    unsigned short* ws    = (unsigned short*)d_ws;
    unsigned short* wsIn  = ws;
    unsigned short* wsHx  = ws + 8388608;
    unsigned short* wsWih = ws + 16777216;
    unsigned short* wsWhh = ws + 18874368;
    unsigned short* wsWc  = ws + 20971520;
    unsigned short* wsWhc = ws + 22020096;
    cvt_all<<<11264, 256, 0, stream>>>(In, Hx, Wih, Whh, Wc, Whc,
                                       wsIn, wsHx, wsWih, wsWhh, wsWc, wsWhc);
    gru_gemm<<<512, 512, 0, stream>>>(wsIn, wsHx, wsWih, wsWhh, wsWc, wsWhc,
                                      Hx, bih, bhh, bc, bhc, out);
  } else {
    gru_fallback<<<2048, 256, 0, stream>>>(In, Hx, Wih, bih, Whh, bhh, Wc, bc, Whc, bhc, out);
  }
}